// Round 1
// baseline (2216.253 us; speedup 1.0000x reference)
//
#include <hip/hip_runtime.h>

#define BATCH 8
#define NPTS 8192
#define NCH 64
#define NPOINT 1024
#define NSAMPLE 32

typedef float f4 __attribute__((ext_vector_type(4)));

// ---------------------------------------------------------------------------
// Furthest point sampling: one block per batch. Sequential over 1024 picks.
// Exact fp32 arithmetic (no fma contraction) so argmax indices match the
// numpy/jax reference bitwise. Tie-break: first (lowest) index wins.
// ---------------------------------------------------------------------------
__global__ __launch_bounds__(512) void fps_kernel(const float* __restrict__ xyz,
                                                  float* __restrict__ newxyz) {
  const int b = blockIdx.x;
  const int tid = threadIdx.x;
  const int lane = tid & 63;
  const int wid = tid >> 6;
  const float* xb = xyz + (size_t)b * NPTS * 3;

  // Each thread owns 16 strided points entirely in registers.
  float px[16], py[16], pz[16], mind[16];
#pragma unroll
  for (int j = 0; j < 16; ++j) {
    int p = tid + j * 512;
    px[j] = xb[p * 3 + 0];
    py[j] = xb[p * 3 + 1];
    pz[j] = xb[p * 3 + 2];
    mind[j] = 1e10f;
  }

  __shared__ float rv[2][8];
  __shared__ int ri[2][8];

  if (tid == 0) {
    // idxs[:,0] = 0
    newxyz[b * (NPOINT * 3) + 0] = xb[0];
    newxyz[b * (NPOINT * 3) + 1] = xb[1];
    newxyz[b * (NPOINT * 3) + 2] = xb[2];
  }

  int last = 0;
  for (int i = 1; i < NPOINT; ++i) {
    // broadcast load of pivot point (same address for all lanes)
    float qx = xb[last * 3 + 0];
    float qy = xb[last * 3 + 1];
    float qz = xb[last * 3 + 2];

    float best = -1.0f;
    int bidx = 0;
#pragma unroll
    for (int j = 0; j < 16; ++j) {
      float dx = __fsub_rn(px[j], qx);
      float dy = __fsub_rn(py[j], qy);
      float dz = __fsub_rn(pz[j], qz);
      float d = __fadd_rn(__fadd_rn(__fmul_rn(dx, dx), __fmul_rn(dy, dy)),
                          __fmul_rn(dz, dz));
      float m = fminf(mind[j], d);
      mind[j] = m;
      if (m > best) { best = m; bidx = tid + j * 512; }  // strict > keeps lowest idx
    }
    // wave-level argmax reduce (64 lanes), tie -> lower index
#pragma unroll
    for (int off = 32; off > 0; off >>= 1) {
      float ov = __shfl_down(best, off);
      int oi = __shfl_down(bidx, off);
      if (ov > best || (ov == best && oi < bidx)) { best = ov; bidx = oi; }
    }
    const int par = i & 1;  // double-buffered partials: one barrier per iter
    if (lane == 0) { rv[par][wid] = best; ri[par][wid] = bidx; }
    __syncthreads();
    float bv = rv[par][0];
    int bi = ri[par][0];
#pragma unroll
    for (int w = 1; w < 8; ++w) {
      float v = rv[par][w];
      int ix = ri[par][w];
      if (v > bv || (v == bv && ix < bi)) { bv = v; bi = ix; }
    }
    last = bi;  // identical on every thread
    if (tid == 0) {
      newxyz[b * (NPOINT * 3) + i * 3 + 0] = xb[bi * 3 + 0];
      newxyz[b * (NPOINT * 3) + i * 3 + 1] = xb[bi * 3 + 1];
      newxyz[b * (NPOINT * 3) + i * 3 + 2] = xb[bi * 3 + 2];
    }
  }
}

// ---------------------------------------------------------------------------
// Ball query: one wave per (b, s) center. Ordered scan, first 32 indices with
// d2 < r^2; pad with first hit (0 if none). Exact fp32 distance arithmetic.
// ---------------------------------------------------------------------------
__global__ __launch_bounds__(256) void ball_kernel(const float* __restrict__ xyz,
                                                   const float* __restrict__ newxyz,
                                                   int* __restrict__ idxout) {
  const int lane = threadIdx.x & 63;
  const int pair = blockIdx.x * 4 + (threadIdx.x >> 6);
  const int b = pair >> 10;
  const float cx = newxyz[pair * 3 + 0];
  const float cy = newxyz[pair * 3 + 1];
  const float cz = newxyz[pair * 3 + 2];
  const float* xb = xyz + (size_t)b * NPTS * 3;
  int* op = idxout + pair * NSAMPLE;

  int cnt = 0;
  int first = 0;
  for (int base = 0; base < NPTS && cnt < NSAMPLE; base += 64) {
    const int p = base + lane;
    const float* pp = xb + p * 3;
    float dx = __fsub_rn(cx, pp[0]);
    float dy = __fsub_rn(cy, pp[1]);
    float dz = __fsub_rn(cz, pp[2]);
    float d2 = __fadd_rn(__fadd_rn(__fmul_rn(dx, dx), __fmul_rn(dy, dy)),
                         __fmul_rn(dz, dz));
    bool pred = d2 < 0.04f;  // strict <, RADIUS^2 in fp32
    unsigned long long m = __ballot(pred);
    if (cnt == 0 && m) first = base + __builtin_ctzll(m);
    int rank = cnt + (int)__popcll(m & ((1ull << lane) - 1ull));
    if (pred && rank < NSAMPLE) op[rank] = p;
    cnt += (int)__popcll(m);
  }
  if (cnt < NSAMPLE) {
    for (int r = cnt + lane; r < NSAMPLE; r += 64) op[r] = first;
  }
}

// ---------------------------------------------------------------------------
// Group + 3-layer MLP + max-pool. One block (256 thr) per (b, s) group.
// Weights staged transposed in LDS (wt[c][o]) so o-lanes read coalesced b128;
// x rows read as b128 broadcast. Register tiles: 4o x 2n (L1/L2), 4o x 4n (L3).
// LDS: xa 32x68 + xb 32x64 + wt 8192 floats = 48.5 KB -> 3 blocks/CU.
// ---------------------------------------------------------------------------
__global__ __launch_bounds__(256) void group_mlp_kernel(
    const float* __restrict__ xyz, const float* __restrict__ feat,
    const float* __restrict__ w0, const float* __restrict__ s0, const float* __restrict__ b0,
    const float* __restrict__ w1, const float* __restrict__ s1, const float* __restrict__ b1,
    const float* __restrict__ w2, const float* __restrict__ s2, const float* __restrict__ b2,
    const int* __restrict__ idxin, const float* __restrict__ newxyz,
    float* __restrict__ outf) {
  __shared__ float xa[32][68];  // layer0 input (3 xyz + 64 feat + 1 zero pad)
  __shared__ float xb[32][64];  // layer1 out; reused as max-reduce buffer
  __shared__ float wt[8192];    // transposed weights of current layer

  const int tid = threadIdx.x;
  const int pair = blockIdx.x;
  const int b = pair >> 10;
  const int s = pair & 1023;

  // ---- gather: 8 threads per sample row ----
  {
    const float cx = newxyz[pair * 3 + 0];
    const float cy = newxyz[pair * 3 + 1];
    const float cz = newxyz[pair * 3 + 2];
    const int n = tid >> 3, k8 = tid & 7;
    const int pid = idxin[pair * NSAMPLE + n];
    const float* fr = feat + ((size_t)(b * NPTS) + pid) * NCH + k8 * 8;
    f4 f0 = *(const f4*)fr;
    f4 f1 = *(const f4*)(fr + 4);
#pragma unroll
    for (int q = 0; q < 4; ++q) xa[n][3 + k8 * 8 + q] = f0[q];
#pragma unroll
    for (int q = 0; q < 4; ++q) xa[n][3 + k8 * 8 + 4 + q] = f1[q];
    if (k8 == 0) {
      const float* pr = xyz + ((size_t)(b * NPTS) + pid) * 3;
      xa[n][0] = pr[0] - cx;
      xa[n][1] = pr[1] - cy;
      xa[n][2] = pr[2] - cz;
      xa[n][67] = 0.f;
    }
  }
  // stage wT0: wt[c*64+o] = w0[o][c], c in [0,68) (c==67 zero pad)
  for (int t = tid; t < 68 * 64; t += 256) {
    int c = t >> 6, o = t & 63;
    wt[t] = (c < 67) ? w0[o * 67 + c] : 0.f;
  }
  __syncthreads();

  // ---- layer 1: K=68(pad), 64 out; xa -> xb ----
  {
    const int ot = tid & 15, nt = tid >> 4;
    float acc[2][4] = {};
    for (int c = 0; c < 68; c += 4) {
      f4 xq0 = *(const f4*)&xa[nt * 2 + 0][c];
      f4 xq1 = *(const f4*)&xa[nt * 2 + 1][c];
#pragma unroll
      for (int cc = 0; cc < 4; ++cc) {
        f4 wq = *(const f4*)&wt[(c + cc) * 64 + ot * 4];
#pragma unroll
        for (int i = 0; i < 4; ++i) {
          acc[0][i] = fmaf(xq0[cc], wq[i], acc[0][i]);
          acc[1][i] = fmaf(xq1[cc], wq[i], acc[1][i]);
        }
      }
    }
    f4 r0, r1;
#pragma unroll
    for (int i = 0; i < 4; ++i) {
      float sc = s0[ot * 4 + i], bi = b0[ot * 4 + i];
      r0[i] = fmaxf(fmaf(acc[0][i], sc, bi), 0.f);
      r1[i] = fmaxf(fmaf(acc[1][i], sc, bi), 0.f);
    }
    *(f4*)&xb[nt * 2 + 0][ot * 4] = r0;
    *(f4*)&xb[nt * 2 + 1][ot * 4] = r1;
  }
  __syncthreads();
  for (int t = tid; t < 64 * 64; t += 256) {
    int c = t >> 6, o = t & 63;
    wt[t] = w1[o * 64 + c];
  }
  __syncthreads();

  // ---- layer 2: K=64, 64 out; xb -> xa ----
  {
    const int ot = tid & 15, nt = tid >> 4;
    float acc[2][4] = {};
    for (int c = 0; c < 64; c += 4) {
      f4 xq0 = *(const f4*)&xb[nt * 2 + 0][c];
      f4 xq1 = *(const f4*)&xb[nt * 2 + 1][c];
#pragma unroll
      for (int cc = 0; cc < 4; ++cc) {
        f4 wq = *(const f4*)&wt[(c + cc) * 64 + ot * 4];
#pragma unroll
        for (int i = 0; i < 4; ++i) {
          acc[0][i] = fmaf(xq0[cc], wq[i], acc[0][i]);
          acc[1][i] = fmaf(xq1[cc], wq[i], acc[1][i]);
        }
      }
    }
    f4 r0, r1;
#pragma unroll
    for (int i = 0; i < 4; ++i) {
      float sc = s1[ot * 4 + i], bi = b1[ot * 4 + i];
      r0[i] = fmaxf(fmaf(acc[0][i], sc, bi), 0.f);
      r1[i] = fmaxf(fmaf(acc[1][i], sc, bi), 0.f);
    }
    *(f4*)&xa[nt * 2 + 0][ot * 4] = r0;
    *(f4*)&xa[nt * 2 + 1][ot * 4] = r1;
  }
  __syncthreads();
  for (int t = tid; t < 64 * 128; t += 256) {
    int c = t >> 7, o = t & 127;
    wt[t] = w2[o * 64 + c];
  }
  __syncthreads();

  // ---- layer 3: K=64, 128 out; xa -> per-thread max over 4 n ----
  {
    const int ot = tid & 31, nt = tid >> 5;
    float acc[4][4] = {};
    for (int c = 0; c < 64; c += 4) {
      f4 xq[4];
#pragma unroll
      for (int j = 0; j < 4; ++j) xq[j] = *(const f4*)&xa[nt * 4 + j][c];
#pragma unroll
      for (int cc = 0; cc < 4; ++cc) {
        f4 wq = *(const f4*)&wt[(c + cc) * 128 + ot * 4];
#pragma unroll
        for (int j = 0; j < 4; ++j) {
#pragma unroll
          for (int i = 0; i < 4; ++i)
            acc[j][i] = fmaf(xq[j][cc], wq[i], acc[j][i]);
        }
      }
    }
    f4 mx;
#pragma unroll
    for (int i = 0; i < 4; ++i) {
      float sc = s2[ot * 4 + i], bi = b2[ot * 4 + i];
      float v0 = fmaxf(fmaf(acc[0][i], sc, bi), 0.f);
      float v1 = fmaxf(fmaf(acc[1][i], sc, bi), 0.f);
      float v2 = fmaxf(fmaf(acc[2][i], sc, bi), 0.f);
      float v3 = fmaxf(fmaf(acc[3][i], sc, bi), 0.f);
      mx[i] = fmaxf(fmaxf(v0, v1), fmaxf(v2, v3));
    }
    float* red = &xb[0][0];  // xb free after layer2 barrier
    *(f4*)&red[nt * 128 + ot * 4] = mx;
    __syncthreads();
    if (tid < 128) {
      float m = red[tid];
#pragma unroll
      for (int w = 1; w < 8; ++w) m = fmaxf(m, red[w * 128 + tid]);
      outf[((size_t)(b * 128 + tid)) * 1024 + s] = m;
    }
  }
}

extern "C" void kernel_launch(void* const* d_in, const int* in_sizes, int n_in,
                              void* d_out, int out_size, void* d_ws, size_t ws_size,
                              hipStream_t stream) {
  const float* xyz = (const float*)d_in[0];
  const float* feat = (const float*)d_in[1];
  const float* w0 = (const float*)d_in[2];
  const float* s0 = (const float*)d_in[3];
  const float* b0 = (const float*)d_in[4];
  const float* w1 = (const float*)d_in[5];
  const float* s1 = (const float*)d_in[6];
  const float* b1 = (const float*)d_in[7];
  const float* w2 = (const float*)d_in[8];
  const float* s2 = (const float*)d_in[9];
  const float* b2 = (const float*)d_in[10];

  float* newxyz = (float*)d_out;                    // (8,1024,3)
  float* outf = (float*)d_out + BATCH * NPOINT * 3; // (8,128,1024)
  int* idxws = (int*)d_ws;                          // (8*1024, 32) ints = 1 MB

  fps_kernel<<<BATCH, 512, 0, stream>>>(xyz, newxyz);
  ball_kernel<<<(BATCH * NPOINT) / 4, 256, 0, stream>>>(xyz, newxyz, idxws);
  group_mlp_kernel<<<BATCH * NPOINT, 256, 0, stream>>>(
      xyz, feat, w0, s0, b0, w1, s1, b1, w2, s2, b2, idxws, newxyz, outf);
}

// Round 2
// 1686.305 us; speedup vs baseline: 1.3143x; 1.3143x over previous
//
#include <hip/hip_runtime.h>

#define BATCH 8
#define NPTS 8192
#define NCH 64
#define NPOINT 1024
#define NSAMPLE 32

typedef float f4 __attribute__((ext_vector_type(4)));

// ---------------------------------------------------------------------------
// Furthest point sampling: one block per batch, 1024 threads (16 waves,
// 4 waves/SIMD for latency hiding). Sequential over 1024 picks.
// Exact fp32 arithmetic (no fma contraction) so argmax indices match the
// reference bitwise. Argmax key: (dist_bits<<32) | ~idx  — nonneg-float
// compare == uint compare; ties pick lowest index via larger ~idx.
// ---------------------------------------------------------------------------
__global__ __launch_bounds__(1024) void fps_kernel(const float* __restrict__ xyz,
                                                   float* __restrict__ newxyz) {
  const int b = blockIdx.x;
  const int tid = threadIdx.x;
  const int lane = tid & 63;
  const int wid = tid >> 6;  // 0..15
  const float* xb = xyz + (size_t)b * NPTS * 3;

  // Each thread owns 8 strided points entirely in registers.
  float px[8], py[8], pz[8], mind[8];
  unsigned int lok[8];
#pragma unroll
  for (int j = 0; j < 8; ++j) {
    int p = tid + j * 1024;
    px[j] = xb[p * 3 + 0];
    py[j] = xb[p * 3 + 1];
    pz[j] = xb[p * 3 + 2];
    mind[j] = 1e10f;
    lok[j] = ~(unsigned int)p;
  }

  __shared__ __align__(16) unsigned long long pk[2][16];

  if (tid == 0) {
    // idxs[:,0] = 0
    newxyz[b * (NPOINT * 3) + 0] = xb[0];
    newxyz[b * (NPOINT * 3) + 1] = xb[1];
    newxyz[b * (NPOINT * 3) + 2] = xb[2];
  }

  int last = 0;
  for (int i = 1; i < NPOINT; ++i) {
    // broadcast load of pivot point (wave-uniform address -> 1 txn/wave)
    float qx = xb[last * 3 + 0];
    float qy = xb[last * 3 + 1];
    float qz = xb[last * 3 + 2];

    unsigned long long k[8];
#pragma unroll
    for (int j = 0; j < 8; ++j) {
      float dx = __fsub_rn(px[j], qx);
      float dy = __fsub_rn(py[j], qy);
      float dz = __fsub_rn(pz[j], qz);
      float d = __fadd_rn(__fadd_rn(__fmul_rn(dx, dx), __fmul_rn(dy, dy)),
                          __fmul_rn(dz, dz));
      float m = fminf(mind[j], d);
      mind[j] = m;
      k[j] = ((unsigned long long)__float_as_uint(m) << 32) | (unsigned long long)lok[j];
    }
    // local argmax: tree over 8 keys (depth 3)
#pragma unroll
    for (int s = 1; s < 8; s <<= 1) {
#pragma unroll
      for (int j = 0; j < 8; j += 2 * s) {
        if (k[j + s] > k[j]) k[j] = k[j + s];
      }
    }
    unsigned long long best = k[0];
    // wave butterfly reduce (commutative max over u64 keys)
#pragma unroll
    for (int off = 32; off > 0; off >>= 1) {
      unsigned long long o = __shfl_down(best, off);
      if (o > best) best = o;
    }
    const int par = i & 1;  // double-buffered partials: one barrier per iter
    if (lane == 0) pk[par][wid] = best;
    __syncthreads();
    // all threads reduce the 16 wave partials (4x ds_read_b128 pairs)
    const ulonglong2* pp = (const ulonglong2*)pk[par];
    ulonglong2 v0 = pp[0];
    unsigned long long r = (v0.x > v0.y) ? v0.x : v0.y;
#pragma unroll
    for (int t = 1; t < 8; ++t) {
      ulonglong2 v = pp[t];
      unsigned long long w = (v.x > v.y) ? v.x : v.y;
      if (w > r) r = w;
    }
    last = (int)(~(unsigned int)r);  // identical on every thread
    if (tid == 0) {
      newxyz[b * (NPOINT * 3) + i * 3 + 0] = xb[last * 3 + 0];
      newxyz[b * (NPOINT * 3) + i * 3 + 1] = xb[last * 3 + 1];
      newxyz[b * (NPOINT * 3) + i * 3 + 2] = xb[last * 3 + 2];
    }
  }
}

// ---------------------------------------------------------------------------
// Ball query: one wave per (b, s) center. Ordered scan, first 32 indices with
// d2 < r^2; pad with first hit (0 if none). Exact fp32 distance arithmetic.
// ---------------------------------------------------------------------------
__global__ __launch_bounds__(256) void ball_kernel(const float* __restrict__ xyz,
                                                   const float* __restrict__ newxyz,
                                                   int* __restrict__ idxout) {
  const int lane = threadIdx.x & 63;
  const int pair = blockIdx.x * 4 + (threadIdx.x >> 6);
  const int b = pair >> 10;
  const float cx = newxyz[pair * 3 + 0];
  const float cy = newxyz[pair * 3 + 1];
  const float cz = newxyz[pair * 3 + 2];
  const float* xb = xyz + (size_t)b * NPTS * 3;
  int* op = idxout + pair * NSAMPLE;

  int cnt = 0;
  int first = 0;
  for (int base = 0; base < NPTS && cnt < NSAMPLE; base += 64) {
    const int p = base + lane;
    const float* pp = xb + p * 3;
    float dx = __fsub_rn(cx, pp[0]);
    float dy = __fsub_rn(cy, pp[1]);
    float dz = __fsub_rn(cz, pp[2]);
    float d2 = __fadd_rn(__fadd_rn(__fmul_rn(dx, dx), __fmul_rn(dy, dy)),
                         __fmul_rn(dz, dz));
    bool pred = d2 < 0.04f;  // strict <, RADIUS^2 in fp32
    unsigned long long m = __ballot(pred);
    if (cnt == 0 && m) first = base + __builtin_ctzll(m);
    int rank = cnt + (int)__popcll(m & ((1ull << lane) - 1ull));
    if (pred && rank < NSAMPLE) op[rank] = p;
    cnt += (int)__popcll(m);
  }
  if (cnt < NSAMPLE) {
    for (int r = cnt + lane; r < NSAMPLE; r += 64) op[r] = first;
  }
}

// ---------------------------------------------------------------------------
// Group + 3-layer MLP + max-pool. One block (256 thr) per (b, s) group.
// Weights staged transposed in LDS (wt[c][o]) so o-lanes read coalesced b128;
// x rows read as b128 broadcast. Register tiles: 4o x 2n (L1/L2), 4o x 4n (L3).
// LDS: xa 32x68 + xb 32x64 + wt 8192 floats = 48.5 KB -> 3 blocks/CU.
// ---------------------------------------------------------------------------
__global__ __launch_bounds__(256) void group_mlp_kernel(
    const float* __restrict__ xyz, const float* __restrict__ feat,
    const float* __restrict__ w0, const float* __restrict__ s0, const float* __restrict__ b0,
    const float* __restrict__ w1, const float* __restrict__ s1, const float* __restrict__ b1,
    const float* __restrict__ w2, const float* __restrict__ s2, const float* __restrict__ b2,
    const int* __restrict__ idxin, const float* __restrict__ newxyz,
    float* __restrict__ outf) {
  __shared__ float xa[32][68];  // layer0 input (3 xyz + 64 feat + 1 zero pad)
  __shared__ float xb[32][64];  // layer1 out; reused as max-reduce buffer
  __shared__ float wt[8192];    // transposed weights of current layer

  const int tid = threadIdx.x;
  const int pair = blockIdx.x;
  const int b = pair >> 10;
  const int s = pair & 1023;

  // ---- gather: 8 threads per sample row ----
  {
    const float cx = newxyz[pair * 3 + 0];
    const float cy = newxyz[pair * 3 + 1];
    const float cz = newxyz[pair * 3 + 2];
    const int n = tid >> 3, k8 = tid & 7;
    const int pid = idxin[pair * NSAMPLE + n];
    const float* fr = feat + ((size_t)(b * NPTS) + pid) * NCH + k8 * 8;
    f4 f0 = *(const f4*)fr;
    f4 f1 = *(const f4*)(fr + 4);
#pragma unroll
    for (int q = 0; q < 4; ++q) xa[n][3 + k8 * 8 + q] = f0[q];
#pragma unroll
    for (int q = 0; q < 4; ++q) xa[n][3 + k8 * 8 + 4 + q] = f1[q];
    if (k8 == 0) {
      const float* pr = xyz + ((size_t)(b * NPTS) + pid) * 3;
      xa[n][0] = pr[0] - cx;
      xa[n][1] = pr[1] - cy;
      xa[n][2] = pr[2] - cz;
      xa[n][67] = 0.f;
    }
  }
  // stage wT0: wt[c*64+o] = w0[o][c], c in [0,68) (c==67 zero pad)
  for (int t = tid; t < 68 * 64; t += 256) {
    int c = t >> 6, o = t & 63;
    wt[t] = (c < 67) ? w0[o * 67 + c] : 0.f;
  }
  __syncthreads();

  // ---- layer 1: K=68(pad), 64 out; xa -> xb ----
  {
    const int ot = tid & 15, nt = tid >> 4;
    float acc[2][4] = {};
    for (int c = 0; c < 68; c += 4) {
      f4 xq0 = *(const f4*)&xa[nt * 2 + 0][c];
      f4 xq1 = *(const f4*)&xa[nt * 2 + 1][c];
#pragma unroll
      for (int cc = 0; cc < 4; ++cc) {
        f4 wq = *(const f4*)&wt[(c + cc) * 64 + ot * 4];
#pragma unroll
        for (int i = 0; i < 4; ++i) {
          acc[0][i] = fmaf(xq0[cc], wq[i], acc[0][i]);
          acc[1][i] = fmaf(xq1[cc], wq[i], acc[1][i]);
        }
      }
    }
    f4 r0, r1;
#pragma unroll
    for (int i = 0; i < 4; ++i) {
      float sc = s0[ot * 4 + i], bi = b0[ot * 4 + i];
      r0[i] = fmaxf(fmaf(acc[0][i], sc, bi), 0.f);
      r1[i] = fmaxf(fmaf(acc[1][i], sc, bi), 0.f);
    }
    *(f4*)&xb[nt * 2 + 0][ot * 4] = r0;
    *(f4*)&xb[nt * 2 + 1][ot * 4] = r1;
  }
  __syncthreads();
  for (int t = tid; t < 64 * 64; t += 256) {
    int c = t >> 6, o = t & 63;
    wt[t] = w1[o * 64 + c];
  }
  __syncthreads();

  // ---- layer 2: K=64, 64 out; xb -> xa ----
  {
    const int ot = tid & 15, nt = tid >> 4;
    float acc[2][4] = {};
    for (int c = 0; c < 64; c += 4) {
      f4 xq0 = *(const f4*)&xb[nt * 2 + 0][c];
      f4 xq1 = *(const f4*)&xb[nt * 2 + 1][c];
#pragma unroll
      for (int cc = 0; cc < 4; ++cc) {
        f4 wq = *(const f4*)&wt[(c + cc) * 64 + ot * 4];
#pragma unroll
        for (int i = 0; i < 4; ++i) {
          acc[0][i] = fmaf(xq0[cc], wq[i], acc[0][i]);
          acc[1][i] = fmaf(xq1[cc], wq[i], acc[1][i]);
        }
      }
    }
    f4 r0, r1;
#pragma unroll
    for (int i = 0; i < 4; ++i) {
      float sc = s1[ot * 4 + i], bi = b1[ot * 4 + i];
      r0[i] = fmaxf(fmaf(acc[0][i], sc, bi), 0.f);
      r1[i] = fmaxf(fmaf(acc[1][i], sc, bi), 0.f);
    }
    *(f4*)&xa[nt * 2 + 0][ot * 4] = r0;
    *(f4*)&xa[nt * 2 + 1][ot * 4] = r1;
  }
  __syncthreads();
  for (int t = tid; t < 64 * 128; t += 256) {
    int c = t >> 7, o = t & 127;
    wt[t] = w2[o * 64 + c];
  }
  __syncthreads();

  // ---- layer 3: K=64, 128 out; xa -> per-thread max over 4 n ----
  {
    const int ot = tid & 31, nt = tid >> 5;
    float acc[4][4] = {};
    for (int c = 0; c < 64; c += 4) {
      f4 xq[4];
#pragma unroll
      for (int j = 0; j < 4; ++j) xq[j] = *(const f4*)&xa[nt * 4 + j][c];
#pragma unroll
      for (int cc = 0; cc < 4; ++cc) {
        f4 wq = *(const f4*)&wt[(c + cc) * 128 + ot * 4];
#pragma unroll
        for (int j = 0; j < 4; ++j) {
#pragma unroll
          for (int i = 0; i < 4; ++i)
            acc[j][i] = fmaf(xq[j][cc], wq[i], acc[j][i]);
        }
      }
    }
    f4 mx;
#pragma unroll
    for (int i = 0; i < 4; ++i) {
      float sc = s2[ot * 4 + i], bi = b2[ot * 4 + i];
      float v0 = fmaxf(fmaf(acc[0][i], sc, bi), 0.f);
      float v1 = fmaxf(fmaf(acc[1][i], sc, bi), 0.f);
      float v2 = fmaxf(fmaf(acc[2][i], sc, bi), 0.f);
      float v3 = fmaxf(fmaf(acc[3][i], sc, bi), 0.f);
      mx[i] = fmaxf(fmaxf(v0, v1), fmaxf(v2, v3));
    }
    float* red = &xb[0][0];  // xb free after layer2 barrier
    *(f4*)&red[nt * 128 + ot * 4] = mx;
    __syncthreads();
    if (tid < 128) {
      float m = red[tid];
#pragma unroll
      for (int w = 1; w < 8; ++w) m = fmaxf(m, red[w * 128 + tid]);
      outf[((size_t)(b * 128 + tid)) * 1024 + s] = m;
    }
  }
}

extern "C" void kernel_launch(void* const* d_in, const int* in_sizes, int n_in,
                              void* d_out, int out_size, void* d_ws, size_t ws_size,
                              hipStream_t stream) {
  const float* xyz = (const float*)d_in[0];
  const float* feat = (const float*)d_in[1];
  const float* w0 = (const float*)d_in[2];
  const float* s0 = (const float*)d_in[3];
  const float* b0 = (const float*)d_in[4];
  const float* w1 = (const float*)d_in[5];
  const float* s1 = (const float*)d_in[6];
  const float* b1 = (const float*)d_in[7];
  const float* w2 = (const float*)d_in[8];
  const float* s2 = (const float*)d_in[9];
  const float* b2 = (const float*)d_in[10];

  float* newxyz = (float*)d_out;                    // (8,1024,3)
  float* outf = (float*)d_out + BATCH * NPOINT * 3; // (8,128,1024)
  int* idxws = (int*)d_ws;                          // (8*1024, 32) ints = 1 MB

  fps_kernel<<<BATCH, 1024, 0, stream>>>(xyz, newxyz);
  ball_kernel<<<(BATCH * NPOINT) / 4, 256, 0, stream>>>(xyz, newxyz, idxws);
  group_mlp_kernel<<<BATCH * NPOINT, 256, 0, stream>>>(
      xyz, feat, w0, s0, b0, w1, s1, b1, w2, s2, b2, idxws, newxyz, outf);
}

// Round 3
// 1604.478 us; speedup vs baseline: 1.3813x; 1.0510x over previous
//
#include <hip/hip_runtime.h>

#define BATCH 8
#define NPTS 8192
#define NCH 64
#define NPOINT 1024
#define NSAMPLE 32

typedef float f4 __attribute__((ext_vector_type(4)));
typedef float f2 __attribute__((ext_vector_type(2)));

// ---------------------------------------------------------------------------
// Furthest point sampling: one block per batch, 1024 threads (16 waves,
// 4 waves/SIMD). Sequential over 1024 picks. Issue-bound on 8 CUs, so the
// structure minimizes VALU ops/iter:
//  - distance update as float2 pairs -> v_pk_add/mul_f32 (packed fp32),
//    contract(off) keeps mul+add rounding identical to the reference
//  - argmax key (dist_bits<<32)|~idx: u64 max == float max with low-idx ties
//  - 5-step half-wave butterfly (2 partials/wave), then wave 0 alone reduces
//    the 32 partials and posts the winner index (2 barriers, no redundant
//    all-thread reduce)
//  - newxyz written once at the end from an LDS index list
// ---------------------------------------------------------------------------
__global__ __launch_bounds__(1024) void fps_kernel(const float* __restrict__ xyz,
                                                   float* __restrict__ newxyz) {
  const int b = blockIdx.x;
  const int tid = threadIdx.x;
  const int lane = tid & 63;
  const int wid = tid >> 6;  // 0..15
  const float* xb = xyz + (size_t)b * NPTS * 3;

  // Each thread owns 8 strided points as 4 float2 pairs, all in registers.
  f2 pxv[4], pyv[4], pzv[4], mindv[4];
  unsigned int lok0[4], lok1[4];
#pragma unroll
  for (int j = 0; j < 4; ++j) {
    int p0 = tid + (2 * j) * 1024;
    int p1 = tid + (2 * j + 1) * 1024;
    pxv[j] = f2{xb[p0 * 3 + 0], xb[p1 * 3 + 0]};
    pyv[j] = f2{xb[p0 * 3 + 1], xb[p1 * 3 + 1]};
    pzv[j] = f2{xb[p0 * 3 + 2], xb[p1 * 3 + 2]};
    mindv[j] = f2{1e10f, 1e10f};
    lok0[j] = ~(unsigned int)p0;
    lok1[j] = ~(unsigned int)p1;
  }

  __shared__ __align__(16) unsigned long long pk[32];  // 2 partials per wave
  __shared__ unsigned int winslot;
  __shared__ unsigned short winidx[NPOINT];

  int last = 0;
  for (int i = 1; i < NPOINT; ++i) {
#pragma clang fp contract(off)
    // broadcast load of pivot point (wave-uniform address -> 1 txn/wave)
    float qx = xb[last * 3 + 0];
    float qy = xb[last * 3 + 1];
    float qz = xb[last * 3 + 2];
    f2 qx2 = f2{qx, qx}, qy2 = f2{qy, qy}, qz2 = f2{qz, qz};

    unsigned long long k[8];
#pragma unroll
    for (int j = 0; j < 4; ++j) {
      f2 dx = pxv[j] - qx2;
      f2 dy = pyv[j] - qy2;
      f2 dz = pzv[j] - qz2;
      f2 d = (dx * dx + dy * dy) + dz * dz;  // same order/rounding as ref
      f2 m = mindv[j];
      m.x = fminf(m.x, d.x);
      m.y = fminf(m.y, d.y);
      mindv[j] = m;
      k[2 * j + 0] = ((unsigned long long)__float_as_uint(m.x) << 32) |
                     (unsigned long long)lok0[j];
      k[2 * j + 1] = ((unsigned long long)__float_as_uint(m.y) << 32) |
                     (unsigned long long)lok1[j];
    }
    // local argmax: tree over 8 keys (depth 3)
#pragma unroll
    for (int s = 1; s < 8; s <<= 1) {
#pragma unroll
      for (int j = 0; j < 8; j += 2 * s) {
        if (k[j + s] > k[j]) k[j] = k[j + s];
      }
    }
    unsigned long long best = k[0];
    // half-wave butterfly (xor 16..1 stays within each 32-lane half)
#pragma unroll
    for (int off = 16; off > 0; off >>= 1) {
      unsigned long long o = __shfl_xor(best, off);
      if (o > best) best = o;
    }
    if ((lane & 31) == 0) pk[wid * 2 + (lane >> 5)] = best;
    __syncthreads();
    if (wid == 0) {
      // wave 0 reduces the 32 partials: each half of the wave reduces all 32
      unsigned long long r = pk[lane & 31];
#pragma unroll
      for (int off = 16; off > 0; off >>= 1) {
        unsigned long long o = __shfl_xor(r, off);
        if (o > r) r = o;
      }
      if (lane == 0) {
        unsigned int idx = ~(unsigned int)r;
        winslot = idx;
        winidx[i] = (unsigned short)idx;
      }
    }
    __syncthreads();
    last = (int)winslot;  // identical on every thread
  }

  // one coalesced pass writes all 1024 sampled points
  {
    const int idx = (tid == 0) ? 0 : (int)winidx[tid];
    const float* pr = xb + idx * 3;
    float* op = newxyz + b * (NPOINT * 3) + tid * 3;
    op[0] = pr[0];
    op[1] = pr[1];
    op[2] = pr[2];
  }
}

// ---------------------------------------------------------------------------
// Ball query: one wave per (b, s) center. Ordered scan, first 32 indices with
// d2 < r^2; pad with first hit (0 if none). Exact fp32 distance arithmetic.
// ---------------------------------------------------------------------------
__global__ __launch_bounds__(256) void ball_kernel(const float* __restrict__ xyz,
                                                   const float* __restrict__ newxyz,
                                                   int* __restrict__ idxout) {
  const int lane = threadIdx.x & 63;
  const int pair = blockIdx.x * 4 + (threadIdx.x >> 6);
  const int b = pair >> 10;
  const float cx = newxyz[pair * 3 + 0];
  const float cy = newxyz[pair * 3 + 1];
  const float cz = newxyz[pair * 3 + 2];
  const float* xb = xyz + (size_t)b * NPTS * 3;
  int* op = idxout + pair * NSAMPLE;

  int cnt = 0;
  int first = 0;
  for (int base = 0; base < NPTS && cnt < NSAMPLE; base += 64) {
    const int p = base + lane;
    const float* pp = xb + p * 3;
    float dx = __fsub_rn(cx, pp[0]);
    float dy = __fsub_rn(cy, pp[1]);
    float dz = __fsub_rn(cz, pp[2]);
    float d2 = __fadd_rn(__fadd_rn(__fmul_rn(dx, dx), __fmul_rn(dy, dy)),
                         __fmul_rn(dz, dz));
    bool pred = d2 < 0.04f;  // strict <, RADIUS^2 in fp32
    unsigned long long m = __ballot(pred);
    if (cnt == 0 && m) first = base + __builtin_ctzll(m);
    int rank = cnt + (int)__popcll(m & ((1ull << lane) - 1ull));
    if (pred && rank < NSAMPLE) op[rank] = p;
    cnt += (int)__popcll(m);
  }
  if (cnt < NSAMPLE) {
    for (int r = cnt + lane; r < NSAMPLE; r += 64) op[r] = first;
  }
}

// ---------------------------------------------------------------------------
// Group + 3-layer MLP + max-pool. One block (256 thr) per (b, s) group.
// Weights staged transposed in LDS (wt[c][o]) so o-lanes read coalesced b128;
// x rows read as b128 broadcast. Register tiles: 4o x 2n (L1/L2), 4o x 4n (L3).
// LDS: xa 32x68 + xb 32x64 + wt 8192 floats = 48.5 KB -> 3 blocks/CU.
// ---------------------------------------------------------------------------
__global__ __launch_bounds__(256) void group_mlp_kernel(
    const float* __restrict__ xyz, const float* __restrict__ feat,
    const float* __restrict__ w0, const float* __restrict__ s0, const float* __restrict__ b0,
    const float* __restrict__ w1, const float* __restrict__ s1, const float* __restrict__ b1,
    const float* __restrict__ w2, const float* __restrict__ s2, const float* __restrict__ b2,
    const int* __restrict__ idxin, const float* __restrict__ newxyz,
    float* __restrict__ outf) {
  __shared__ float xa[32][68];  // layer0 input (3 xyz + 64 feat + 1 zero pad)
  __shared__ float xb[32][64];  // layer1 out; reused as max-reduce buffer
  __shared__ float wt[8192];    // transposed weights of current layer

  const int tid = threadIdx.x;
  const int pair = blockIdx.x;
  const int b = pair >> 10;
  const int s = pair & 1023;

  // ---- gather: 8 threads per sample row ----
  {
    const float cx = newxyz[pair * 3 + 0];
    const float cy = newxyz[pair * 3 + 1];
    const float cz = newxyz[pair * 3 + 2];
    const int n = tid >> 3, k8 = tid & 7;
    const int pid = idxin[pair * NSAMPLE + n];
    const float* fr = feat + ((size_t)(b * NPTS) + pid) * NCH + k8 * 8;
    f4 f0 = *(const f4*)fr;
    f4 f1 = *(const f4*)(fr + 4);
#pragma unroll
    for (int q = 0; q < 4; ++q) xa[n][3 + k8 * 8 + q] = f0[q];
#pragma unroll
    for (int q = 0; q < 4; ++q) xa[n][3 + k8 * 8 + 4 + q] = f1[q];
    if (k8 == 0) {
      const float* pr = xyz + ((size_t)(b * NPTS) + pid) * 3;
      xa[n][0] = pr[0] - cx;
      xa[n][1] = pr[1] - cy;
      xa[n][2] = pr[2] - cz;
      xa[n][67] = 0.f;
    }
  }
  // stage wT0: wt[c*64+o] = w0[o][c], c in [0,68) (c==67 zero pad)
  for (int t = tid; t < 68 * 64; t += 256) {
    int c = t >> 6, o = t & 63;
    wt[t] = (c < 67) ? w0[o * 67 + c] : 0.f;
  }
  __syncthreads();

  // ---- layer 1: K=68(pad), 64 out; xa -> xb ----
  {
    const int ot = tid & 15, nt = tid >> 4;
    float acc[2][4] = {};
    for (int c = 0; c < 68; c += 4) {
      f4 xq0 = *(const f4*)&xa[nt * 2 + 0][c];
      f4 xq1 = *(const f4*)&xa[nt * 2 + 1][c];
#pragma unroll
      for (int cc = 0; cc < 4; ++cc) {
        f4 wq = *(const f4*)&wt[(c + cc) * 64 + ot * 4];
#pragma unroll
        for (int i = 0; i < 4; ++i) {
          acc[0][i] = fmaf(xq0[cc], wq[i], acc[0][i]);
          acc[1][i] = fmaf(xq1[cc], wq[i], acc[1][i]);
        }
      }
    }
    f4 r0, r1;
#pragma unroll
    for (int i = 0; i < 4; ++i) {
      float sc = s0[ot * 4 + i], bi = b0[ot * 4 + i];
      r0[i] = fmaxf(fmaf(acc[0][i], sc, bi), 0.f);
      r1[i] = fmaxf(fmaf(acc[1][i], sc, bi), 0.f);
    }
    *(f4*)&xb[nt * 2 + 0][ot * 4] = r0;
    *(f4*)&xb[nt * 2 + 1][ot * 4] = r1;
  }
  __syncthreads();
  for (int t = tid; t < 64 * 64; t += 256) {
    int c = t >> 6, o = t & 63;
    wt[t] = w1[o * 64 + c];
  }
  __syncthreads();

  // ---- layer 2: K=64, 64 out; xb -> xa ----
  {
    const int ot = tid & 15, nt = tid >> 4;
    float acc[2][4] = {};
    for (int c = 0; c < 64; c += 4) {
      f4 xq0 = *(const f4*)&xb[nt * 2 + 0][c];
      f4 xq1 = *(const f4*)&xb[nt * 2 + 1][c];
#pragma unroll
      for (int cc = 0; cc < 4; ++cc) {
        f4 wq = *(const f4*)&wt[(c + cc) * 64 + ot * 4];
#pragma unroll
        for (int i = 0; i < 4; ++i) {
          acc[0][i] = fmaf(xq0[cc], wq[i], acc[0][i]);
          acc[1][i] = fmaf(xq1[cc], wq[i], acc[1][i]);
        }
      }
    }
    f4 r0, r1;
#pragma unroll
    for (int i = 0; i < 4; ++i) {
      float sc = s1[ot * 4 + i], bi = b1[ot * 4 + i];
      r0[i] = fmaxf(fmaf(acc[0][i], sc, bi), 0.f);
      r1[i] = fmaxf(fmaf(acc[1][i], sc, bi), 0.f);
    }
    *(f4*)&xa[nt * 2 + 0][ot * 4] = r0;
    *(f4*)&xa[nt * 2 + 1][ot * 4] = r1;
  }
  __syncthreads();
  for (int t = tid; t < 64 * 128; t += 256) {
    int c = t >> 7, o = t & 127;
    wt[t] = w2[o * 64 + c];
  }
  __syncthreads();

  // ---- layer 3: K=64, 128 out; xa -> per-thread max over 4 n ----
  {
    const int ot = tid & 31, nt = tid >> 5;
    float acc[4][4] = {};
    for (int c = 0; c < 64; c += 4) {
      f4 xq[4];
#pragma unroll
      for (int j = 0; j < 4; ++j) xq[j] = *(const f4*)&xa[nt * 4 + j][c];
#pragma unroll
      for (int cc = 0; cc < 4; ++cc) {
        f4 wq = *(const f4*)&wt[(c + cc) * 128 + ot * 4];
#pragma unroll
        for (int j = 0; j < 4; ++j) {
#pragma unroll
          for (int i = 0; i < 4; ++i)
            acc[j][i] = fmaf(xq[j][cc], wq[i], acc[j][i]);
        }
      }
    }
    f4 mx;
#pragma unroll
    for (int i = 0; i < 4; ++i) {
      float sc = s2[ot * 4 + i], bi = b2[ot * 4 + i];
      float v0 = fmaxf(fmaf(acc[0][i], sc, bi), 0.f);
      float v1 = fmaxf(fmaf(acc[1][i], sc, bi), 0.f);
      float v2 = fmaxf(fmaf(acc[2][i], sc, bi), 0.f);
      float v3 = fmaxf(fmaf(acc[3][i], sc, bi), 0.f);
      mx[i] = fmaxf(fmaxf(v0, v1), fmaxf(v2, v3));
    }
    float* red = &xb[0][0];  // xb free after layer2 barrier
    *(f4*)&red[nt * 128 + ot * 4] = mx;
    __syncthreads();
    if (tid < 128) {
      float m = red[tid];
#pragma unroll
      for (int w = 1; w < 8; ++w) m = fmaxf(m, red[w * 128 + tid]);
      outf[((size_t)(b * 128 + tid)) * 1024 + s] = m;
    }
  }
}

extern "C" void kernel_launch(void* const* d_in, const int* in_sizes, int n_in,
                              void* d_out, int out_size, void* d_ws, size_t ws_size,
                              hipStream_t stream) {
  const float* xyz = (const float*)d_in[0];
  const float* feat = (const float*)d_in[1];
  const float* w0 = (const float*)d_in[2];
  const float* s0 = (const float*)d_in[3];
  const float* b0 = (const float*)d_in[4];
  const float* w1 = (const float*)d_in[5];
  const float* s1 = (const float*)d_in[6];
  const float* b1 = (const float*)d_in[7];
  const float* w2 = (const float*)d_in[8];
  const float* s2 = (const float*)d_in[9];
  const float* b2 = (const float*)d_in[10];

  float* newxyz = (float*)d_out;                    // (8,1024,3)
  float* outf = (float*)d_out + BATCH * NPOINT * 3; // (8,128,1024)
  int* idxws = (int*)d_ws;                          // (8*1024, 32) ints = 1 MB

  fps_kernel<<<BATCH, 1024, 0, stream>>>(xyz, newxyz);
  ball_kernel<<<(BATCH * NPOINT) / 4, 256, 0, stream>>>(xyz, newxyz, idxws);
  group_mlp_kernel<<<BATCH * NPOINT, 256, 0, stream>>>(
      xyz, feat, w0, s0, b0, w1, s1, b1, w2, s2, b2, idxws, newxyz, outf);
}